// Round 3
// baseline (206.999 us; speedup 1.0000x reference)
//
#include <hip/hip_runtime.h>
#include <hip/hip_bf16.h>

#define HW 3136
#define HH 56
#define WW 56
#define BB 4
#define CC 256
#define HD 128

// attention tile geometry
#define TH 4
#define TW 8
#define WR 8    // TH+4
#define WC 12   // TW+4
#define WPX 96  // WR*WC
#define KS2 136 // ushorts per window pixel: 128 + 8 pad (272B stride)

// MFMA GEMM geometry: LDS row = 64 bf16 + pad -> 72 (144 B)
#define ASTR 72
// y2 LDS row: 256 bf16 + pad -> 264 (528 B, 16B-multiple)
#define YSTR 264

typedef __attribute__((ext_vector_type(8))) short bf16x8;
typedef __attribute__((ext_vector_type(4))) float f32x4;

__device__ __forceinline__ unsigned short f2bf(float f) {
    unsigned int u; __builtin_memcpy(&u, &f, 4);
    unsigned int r = u + 0x7FFFu + ((u >> 16) & 1u);   // RNE
    return (unsigned short)(r >> 16);
}
__device__ __forceinline__ float bflo(unsigned int u) {
    unsigned int x = u << 16; float f; __builtin_memcpy(&f, &x, 4); return f;
}
__device__ __forceinline__ float bfhi(unsigned int u) {
    unsigned int x = u & 0xFFFF0000u; float f; __builtin_memcpy(&f, &x, 4); return f;
}
__device__ __forceinline__ void unpk8(uint4 u, float* f) {
    f[0] = bflo(u.x); f[1] = bfhi(u.x); f[2] = bflo(u.y); f[3] = bfhi(u.y);
    f[4] = bflo(u.z); f[5] = bfhi(u.z); f[6] = bflo(u.w); f[7] = bfhi(u.w);
}
__device__ __forceinline__ uint4 pack8(float4 a, float4 b) {
    uint4 pk;
    pk.x = (unsigned int)f2bf(a.x) | ((unsigned int)f2bf(a.y) << 16);
    pk.y = (unsigned int)f2bf(a.z) | ((unsigned int)f2bf(a.w) << 16);
    pk.z = (unsigned int)f2bf(b.x) | ((unsigned int)f2bf(b.y) << 16);
    pk.w = (unsigned int)f2bf(b.z) | ((unsigned int)f2bf(b.w) << 16);
    return pk;
}

// ---------------- K1: qkv direct from fp32 x (NCHW) + fp32 W -----------------
// A-tile transposed on the fly during LDS staging. grid (98, 2, 3), 256 thr.
__global__ __launch_bounds__(256) void qkv_direct(
    const float* __restrict__ x,
    const float* __restrict__ Wq, const float* __restrict__ Wk,
    const float* __restrict__ Wv,
    unsigned short* __restrict__ q_ws, unsigned short* __restrict__ k_ws,
    unsigned short* __restrict__ v_ws, float* __restrict__ psum)
{
    int wsel = blockIdx.z;
    const float* wsrc = (wsel == 0) ? Wq : ((wsel == 1) ? Wk : Wv);
    unsigned short* outp = (wsel == 0) ? q_ws : ((wsel == 1) ? k_ws : v_ws);
    int gp0 = blockIdx.x * 128, o0 = blockIdx.y * 128;
    int t = threadIdx.x;

    if (blockIdx.x == 0 && blockIdx.y == 0 && wsel == 0 && t < 64) psum[t] = 0.f;

    __shared__ unsigned short As[128 * ASTR];
    __shared__ unsigned short Bs[128 * ASTR];

    int wave = t >> 6, lane = t & 63;
    int mo = (wave & 1) * 64, no = (wave >> 1) * 64;
    int lm = lane & 15, lq = lane >> 4;
    int sr = t >> 3, sc = t & 7;

    // A staging map: 4-pixel groups x channel pairs
    int tpx = t & 31, tch = t >> 5;            // tpx 0..31, tch 0..7
    int gpa = gp0 + 4 * tpx;
    int ba = gpa / HW;
    int pa = gpa - ba * HW;
    const float* xb = x + (size_t)ba * CC * HW + pa;

    f32x4 acc[4][4];
#pragma unroll
    for (int i = 0; i < 4; i++)
#pragma unroll
        for (int j = 0; j < 4; j++) acc[i][j] = (f32x4){0.f, 0.f, 0.f, 0.f};

    for (int k0 = 0; k0 < 256; k0 += 64) {
        // B: 128 rows x 64 cols from fp32 weights
#pragma unroll
        for (int i = 0; i < 4; i++) {
            int r = sr + 32 * i;
            const float* wr = wsrc + (size_t)(o0 + r) * CC + k0 + sc * 8;
            float4 w0 = *(const float4*)wr;
            float4 w1 = *(const float4*)(wr + 4);
            *(uint4*)&Bs[r * ASTR + sc * 8] = pack8(w0, w1);
        }
        // A: 128 px x 64 ch, transposed from x
#pragma unroll
        for (int i = 0; i < 4; i++) {
            int cr = 2 * tch + 16 * i;         // even col 0..62
            int c = k0 + cr;
            float4 f0 = *(const float4*)(xb + (size_t)c * HW);
            float4 f1 = *(const float4*)(xb + (size_t)(c + 1) * HW);
            const float* p0 = (const float*)&f0;
            const float* p1 = (const float*)&f1;
#pragma unroll
            for (int j = 0; j < 4; j++) {
                unsigned int pk = (unsigned int)f2bf(p0[j]) |
                                  ((unsigned int)f2bf(p1[j]) << 16);
                *(unsigned int*)&As[(4 * tpx + j) * ASTR + cr] = pk;
            }
        }
        __syncthreads();
#pragma unroll
        for (int ks = 0; ks < 64; ks += 32) {
            bf16x8 af[4], bfr[4];
#pragma unroll
            for (int i = 0; i < 4; i++)
                af[i] = *(bf16x8*)&As[(mo + 16 * i + lm) * ASTR + ks + lq * 8];
#pragma unroll
            for (int j = 0; j < 4; j++)
                bfr[j] = *(bf16x8*)&Bs[(no + 16 * j + lm) * ASTR + ks + lq * 8];
#pragma unroll
            for (int i = 0; i < 4; i++)
#pragma unroll
                for (int j = 0; j < 4; j++)
                    acc[i][j] = __builtin_amdgcn_mfma_f32_16x16x32_bf16(
                        af[i], bfr[j], acc[i][j], 0, 0, 0);
        }
        __syncthreads();
    }
    unsigned short* ob = outp + (size_t)gp0 * CC + o0;
    bool ev = (lm & 1) == 0;
    int elm = lm & ~1;
#pragma unroll
    for (int i = 0; i < 4; i++)
#pragma unroll
        for (int j = 0; j < 4; j++)
#pragma unroll
            for (int r = 0; r < 4; r++) {
                float v = acc[i][j][r];
                float p = __shfl_xor(v, 1, 64);
                unsigned int pk = ev
                    ? ((unsigned int)f2bf(v) | ((unsigned int)f2bf(p) << 16))
                    : ((unsigned int)f2bf(p) | ((unsigned int)f2bf(v) << 16));
                if (ev == (r < 2)) {
                    int m = mo + 16 * i + lq * 4 + r;
                    int n = no + 16 * j + elm;
                    *(unsigned int*)(ob + (size_t)m * CC + n) = pk;
                }
            }
}

// ---------------- K2: local attention, bf16 LDS, single staging pass ---------
__global__ __launch_bounds__(256) void attn_kernel(
    const unsigned short* __restrict__ q_ws, const unsigned short* __restrict__ k_ws,
    const unsigned short* __restrict__ v_ws,
    const float* __restrict__ rel_h, const float* __restrict__ rel_w,
    unsigned short* __restrict__ ao_ws)
{
    __shared__ unsigned short kwin[WPX * KS2];   // 26112 B
    __shared__ unsigned short vwin[WPX * KS2];   // 26112 B (52.2 KB -> 3 blk/CU)

    int t = threadIdx.x;
    int tile = blockIdx.x;
    int n = blockIdx.y;
    int b = blockIdx.z;
    int tr = tile / 7, tc = tile - tr * 7;
    int h0 = tr * TH, w0 = tc * TW;
    const size_t base = (size_t)b * HW * CC + n * HD;
    const float* relp = (n == 0) ? rel_h : rel_w;

    {   // stage k AND v as bf16 (raw copies)
        int c8 = t & 15, pw0 = t >> 4;
#pragma unroll
        for (int it = 0; it < 6; it++) {
            int pw = pw0 + it * 16;
            int wr = pw / 12, wc = pw - wr * 12;
            int gh = h0 + wr - 2, gw = w0 + wc - 2;
            uint4 uk = make_uint4(0u, 0u, 0u, 0u);
            uint4 uv = make_uint4(0u, 0u, 0u, 0u);
            if (gh >= 0 && gh < HH && gw >= 0 && gw < WW) {
                size_t off = base + (size_t)(gh * WW + gw) * CC + c8 * 8;
                uk = *(const uint4*)(k_ws + off);
                uv = *(const uint4*)(v_ws + off);
            }
            *(uint4*)&kwin[pw * KS2 + c8 * 8] = uk;
            *(uint4*)&vwin[pw * KS2 + c8 * 8] = uv;
        }
    }

    int px = t >> 3, c4g = t & 7;            // pixel 0..31, 16-ch group 0..7
    int pr = px >> 3, pc = px & 7;
    int ghp = h0 + pr, gwp = w0 + pc;
    const size_t pbase = base + (size_t)(ghp * WW + gwp) * CC;

    float qf[16];
    {
        uint4 u0 = *(const uint4*)(q_ws + pbase + c4g * 16);
        uint4 u1 = *(const uint4*)(q_ws + pbase + c4g * 16 + 8);
        unpk8(u0, qf); unpk8(u1, qf + 8);
    }

    // q . rel : direct global reads (2.5 KB table, L1-hot)
    float acc[30];
#pragma unroll
    for (int tt = 0; tt < 5; tt++) acc[25 + tt] = 0.f;
    {
        int c0 = c4g * 16;
#pragma unroll
        for (int c = 0; c < 16; c++) {
            const float* rr = relp + (size_t)(c0 + c) * 5;
            float qc = qf[c];
            acc[25] += qc * rr[0]; acc[26] += qc * rr[1];
            acc[27] += qc * rr[2]; acc[28] += qc * rr[3];
            acc[29] += qc * rr[4];
        }
    }

    __syncthreads();   // staging complete; only barrier in kernel

    // scores: q . k
#pragma unroll
    for (int tt = 0; tt < 25; tt++) {
        int di = tt / 5, dj = tt - 5 * di;
        const unsigned short* kp = &kwin[((pr + di) * WC + pc + dj) * KS2 + c4g * 16];
        float kf[16];
        unpk8(*(const uint4*)kp, kf);
        unpk8(*(const uint4*)(kp + 8), kf + 8);
        float s = 0.f;
#pragma unroll
        for (int c = 0; c < 16; c++) s += qf[c] * kf[c];
        acc[tt] = s;
    }

#pragma unroll
    for (int tt = 0; tt < 30; tt++) {
#pragma unroll
        for (int m = 1; m < 8; m <<= 1)
            acc[tt] += __shfl_xor(acc[tt], m, 64);
    }

    // register softmax
    {
        const float inv = 0.08838834764831845f;
        float mx = -1e30f;
#pragma unroll
        for (int tt = 0; tt < 25; tt++) {
            int di = tt / 5, dj = tt - 5 * (tt / 5);
            acc[tt] = (acc[tt] + ((n == 0) ? acc[25 + di] : acc[25 + dj])) * inv;
            mx = fmaxf(mx, acc[tt]);
        }
        float sum = 0.f;
#pragma unroll
        for (int tt = 0; tt < 25; tt++) { acc[tt] = __expf(acc[tt] - mx); sum += acc[tt]; }
        float rs = 1.f / sum;
#pragma unroll
        for (int tt = 0; tt < 25; tt++) acc[tt] *= rs;
    }

    // PV
    float oacc[16];
#pragma unroll
    for (int c = 0; c < 16; c++) oacc[c] = 0.f;
#pragma unroll
    for (int tt = 0; tt < 25; tt++) {
        int di = tt / 5, dj = tt - 5 * di;
        const unsigned short* vp = &vwin[((pr + di) * WC + pc + dj) * KS2 + c4g * 16];
        float vf[16];
        unpk8(*(const uint4*)vp, vf);
        unpk8(*(const uint4*)(vp + 8), vf + 8);
        float a = acc[tt];
#pragma unroll
        for (int c = 0; c < 16; c++) oacc[c] += a * vf[c];
    }

    unsigned short pk[16];
#pragma unroll
    for (int c = 0; c < 16; c++) pk[c] = f2bf(oacc[c]);
    *(uint4*)(ao_ws + pbase + c4g * 16)     = *(uint4*)pk;
    *(uint4*)(ao_ws + pbase + c4g * 16 + 8) = *(uint4*)&pk[8];
}

// ---------------- K3: agg (BN1+ReLU -> 1x1 conv -> BN2) fused with SE squeeze
// tile 32 px x 256 out, grid 392 x 256 thr. y2 never leaves LDS.
__global__ __launch_bounds__(256) void agg_se(
    const unsigned short* __restrict__ ao, const float* __restrict__ Wa,
    const float* __restrict__ g1, const float* __restrict__ b1,
    const float* __restrict__ m1, const float* __restrict__ v1,
    const float* __restrict__ g2, const float* __restrict__ b2,
    const float* __restrict__ m2, const float* __restrict__ v2,
    const float* __restrict__ Wse,
    const float* __restrict__ gin, const float* __restrict__ bin,
    const float* __restrict__ min_, const float* __restrict__ vin,
    float* __restrict__ s_ws, float* __restrict__ psum)
{
    int gp0 = blockIdx.x * 32;
    __shared__ unsigned short As[32 * ASTR];     // 4.6 KB
    __shared__ unsigned short Bs[256 * ASTR];    // 36.9 KB
    __shared__ unsigned short ybuf[32 * YSTR];   // 16.9 KB
    __shared__ float s1[256], o1[256], s2[256], o2[256];  // 4 KB  (total 62.4 KB)

    int t = threadIdx.x;
    {
        float sc1 = g1[t] * rsqrtf(v1[t] + 1e-5f);
        s1[t] = sc1; o1[t] = b1[t] - m1[t] * sc1;
        float sc2 = g2[t] * rsqrtf(v2[t] + 1e-5f);
        s2[t] = sc2; o2[t] = b2[t] - m2[t] * sc2;
    }

    int wave = t >> 6, lane = t & 63;
    int lm = lane & 15, lq = lane >> 4;
    int asr = t >> 3, asc = t & 7;

    f32x4 acc[2][4];
#pragma unroll
    for (int i = 0; i < 2; i++)
#pragma unroll
        for (int j = 0; j < 4; j++) acc[i][j] = (f32x4){0.f, 0.f, 0.f, 0.f};

    __syncthreads();

    for (int k0 = 0; k0 < 256; k0 += 64) {
        {   // A: 32 px x 64 ch from bf16 ao, BN1+ReLU fused
            int cb = k0 + asc * 8;
            uint4 u = *(const uint4*)(ao + (size_t)(gp0 + asr) * CC + cb);
            float e[8]; unpk8(u, e);
            unsigned short pk[8];
#pragma unroll
            for (int uu = 0; uu < 8; uu++)
                pk[uu] = f2bf(fmaxf(e[uu] * s1[cb + uu] + o1[cb + uu], 0.f));
            *(uint4*)&As[asr * ASTR + asc * 8] = *(uint4*)pk;
        }
        // B: 256 rows x 64 cols from fp32 agg_W
#pragma unroll
        for (int i = 0; i < 8; i++) {
            int r = asr + 32 * i;
            const float* wr = Wa + (size_t)r * CC + k0 + asc * 8;
            float4 w0 = *(const float4*)wr;
            float4 w1 = *(const float4*)(wr + 4);
            *(uint4*)&Bs[r * ASTR + asc * 8] = pack8(w0, w1);
        }
        __syncthreads();
#pragma unroll
        for (int ks = 0; ks < 64; ks += 32) {
            bf16x8 af[2], bfr[4];
#pragma unroll
            for (int i = 0; i < 2; i++)
                af[i] = *(bf16x8*)&As[(16 * i + lm) * ASTR + ks + lq * 8];
#pragma unroll
            for (int j = 0; j < 4; j++)
                bfr[j] = *(bf16x8*)&Bs[(wave * 64 + 16 * j + lm) * ASTR + ks + lq * 8];
#pragma unroll
            for (int i = 0; i < 2; i++)
#pragma unroll
                for (int j = 0; j < 4; j++)
                    acc[i][j] = __builtin_amdgcn_mfma_f32_16x16x32_bf16(
                        af[i], bfr[j], acc[i][j], 0, 0, 0);
        }
        __syncthreads();
    }

    // BN2 + pack y2 bf16 into ybuf (shfl pair trick)
    {
        bool ev = (lm & 1) == 0;
        int elm = lm & ~1;
#pragma unroll
        for (int i = 0; i < 2; i++)
#pragma unroll
            for (int j = 0; j < 4; j++)
#pragma unroll
                for (int r = 0; r < 4; r++) {
                    int nf = wave * 64 + 16 * j + lm;
                    float v = acc[i][j][r] * s2[nf] + o2[nf];
                    float p = __shfl_xor(v, 1, 64);
                    unsigned int pk = ev
                        ? ((unsigned int)f2bf(v) | ((unsigned int)f2bf(p) << 16))
                        : ((unsigned int)f2bf(p) | ((unsigned int)f2bf(v) << 16));
                    if (ev == (r < 2)) {
                        int m = 16 * i + lq * 4 + r;
                        int nn = wave * 64 + 16 * j + elm;
                        *(unsigned int*)&ybuf[m * YSTR + nn] = pk;
                    }
                }
    }
    __syncthreads();

    // SE squeeze: s[32 px][16] = relu(bn_in(y2 @ Wse^T)); waves 0,1 only
    if (wave < 2) {
        f32x4 sa = (f32x4){0.f, 0.f, 0.f, 0.f};
#pragma unroll
        for (int k0 = 0; k0 < 256; k0 += 32) {
            bf16x8 a = *(bf16x8*)&ybuf[(wave * 16 + lm) * YSTR + k0 + lq * 8];
            const float* wr = Wse + (size_t)lm * CC + k0 + lq * 8;
            float4 w0 = *(const float4*)wr;
            float4 w1 = *(const float4*)(wr + 4);
            uint4 pw = pack8(w0, w1);
            bf16x8 bw = *(bf16x8*)&pw;
            sa = __builtin_amdgcn_mfma_f32_16x16x32_bf16(a, bw, sa, 0, 0, 0);
        }
        float scn = gin[lm] * rsqrtf(vin[lm] + 1e-5f);
        float offn = bin[lm] - min_[lm] * scn;
        int b = gp0 / HW;
        float part = 0.f;
#pragma unroll
        for (int r = 0; r < 4; r++) {
            int px = wave * 16 + lq * 4 + r;
            float sv = fmaxf(sa[r] * scn + offn, 0.f);
            s_ws[(size_t)(gp0 + px) * 16 + lm] = sv;
            part += sv;
        }
        part += __shfl_xor(part, 16, 64);
        part += __shfl_xor(part, 32, 64);
        if (lane < 16) atomicAdd(&psum[b * 16 + lane], part);
    }
}

// ---------------- K4: SE gate + excite conv + BN + fp32 store (NCHW) ---------
__global__ __launch_bounds__(256) void se_out_kernel(
    const float* __restrict__ s_ws, const float* __restrict__ psum,
    const float* __restrict__ fc1, const float* __restrict__ fc2,
    const float* __restrict__ se_Wout,
    const float* __restrict__ gout, const float* __restrict__ bout,
    const float* __restrict__ mout, const float* __restrict__ vout,
    float* __restrict__ out)
{
    int b = blockIdx.y;
    int px0 = blockIdx.x * 32;
    __shared__ float sl[32 * 17];
    __shared__ float wg[256 * 20];
    __shared__ float bo[256];
    __shared__ float gg[16];
    int t = threadIdx.x;

    if (t < 16) {   // gate, redundant per block
        float h = 0.f;
#pragma unroll
        for (int jj = 0; jj < 16; jj++)
            h += (psum[b * 16 + jj] * (1.f / 3136.f)) * fc1[jj];
        h = fmaxf(h, 0.f);
        float z = h * fc2[t];
        gg[t] = 1.f / (1.f + __expf(-z));
    }
    {
        const float* sb = s_ws + (size_t)(b * HW + px0) * 16;
#pragma unroll
        for (int i = 0; i < 2; i++) {
            int idx = t + 256 * i;
            sl[(idx >> 4) * 17 + (idx & 15)] = sb[idx];
        }
    }
    __syncthreads();
    {   // fold weights: wg[o][k] = Wout[o][k] * g[k] * sc2[o]
        float sc = gout[t] * rsqrtf(vout[t] + 1e-5f);
        bo[t] = bout[t] - mout[t] * sc;
        const float* wr = se_Wout + (size_t)t * 16;
#pragma unroll
        for (int k = 0; k < 16; k++)
            wg[t * 20 + k] = wr[k] * gg[k] * sc;
    }
    __syncthreads();

    int px = t & 31, og = t >> 5;          // 8 groups x 32 o
    float4 s0 = *(float4*)&sl[px * 17 + 0];
    float4 s1v = *(float4*)&sl[px * 17 + 4];
    float4 s2v = *(float4*)&sl[px * 17 + 8];
    float4 s3 = *(float4*)&sl[px * 17 + 12];
    float* ob = out + (size_t)b * CC * HW + px0 + px;
#pragma unroll
    for (int oi = 0; oi < 32; oi++) {
        int o = og * 32 + oi;
        float4 w0 = *(float4*)&wg[o * 20 + 0];
        float4 w1 = *(float4*)&wg[o * 20 + 4];
        float4 w2 = *(float4*)&wg[o * 20 + 8];
        float4 w3 = *(float4*)&wg[o * 20 + 12];
        float r = bo[o]
            + s0.x * w0.x + s0.y * w0.y + s0.z * w0.z + s0.w * w0.w
            + s1v.x * w1.x + s1v.y * w1.y + s1v.z * w1.z + s1v.w * w1.w
            + s2v.x * w2.x + s2v.y * w2.y + s2v.z * w2.z + s2v.w * w2.w
            + s3.x * w3.x + s3.y * w3.y + s3.z * w3.z + s3.w * w3.w;
        ob[(size_t)o * HW] = r;
    }
}

extern "C" void kernel_launch(void* const* d_in, const int* in_sizes, int n_in,
                              void* d_out, int out_size, void* d_ws, size_t ws_size,
                              hipStream_t stream) {
    const float* x     = (const float*)d_in[0];
    const float* Wq    = (const float*)d_in[1];
    const float* Wk    = (const float*)d_in[2];
    const float* Wv    = (const float*)d_in[3];
    const float* rel_h = (const float*)d_in[4];
    const float* rel_w = (const float*)d_in[5];
    const float* agg_g1 = (const float*)d_in[6];
    const float* agg_b1 = (const float*)d_in[7];
    const float* agg_m1 = (const float*)d_in[8];
    const float* agg_v1 = (const float*)d_in[9];
    const float* agg_W  = (const float*)d_in[10];
    const float* agg_g2 = (const float*)d_in[11];
    const float* agg_b2 = (const float*)d_in[12];
    const float* agg_m2 = (const float*)d_in[13];
    const float* agg_v2 = (const float*)d_in[14];
    const float* se_Win = (const float*)d_in[15];
    const float* se_g_in = (const float*)d_in[16];
    const float* se_b_in = (const float*)d_in[17];
    const float* se_m_in = (const float*)d_in[18];
    const float* se_v_in = (const float*)d_in[19];
    const float* se_fc1  = (const float*)d_in[20];
    const float* se_fc2  = (const float*)d_in[21];
    const float* se_Wout = (const float*)d_in[22];
    const float* se_g_out = (const float*)d_in[23];
    const float* se_b_out = (const float*)d_in[24];
    const float* se_m_out = (const float*)d_in[25];
    const float* se_v_out = (const float*)d_in[26];

    const size_t NQ = (size_t)BB * HW * CC;   // 3,211,264
    unsigned short* q_ws  = (unsigned short*)d_ws;   // bf16, NQ each
    unsigned short* k_ws  = q_ws + NQ;
    unsigned short* v_ws  = k_ws + NQ;
    unsigned short* ao_ws = v_ws + NQ;
    float* s_ws  = (float*)(ao_ws + NQ);
    float* psum  = s_ws + (size_t)BB * HW * 16;

    qkv_direct<<<dim3(98, 2, 3), 256, 0, stream>>>(x, Wq, Wk, Wv,
                                                   q_ws, k_ws, v_ws, psum);
    attn_kernel<<<dim3(98, 2, 4), 256, 0, stream>>>(q_ws, k_ws, v_ws,
                                                    rel_h, rel_w, ao_ws);
    agg_se<<<dim3(392), 256, 0, stream>>>(ao_ws, agg_W,
        agg_g1, agg_b1, agg_m1, agg_v1, agg_g2, agg_b2, agg_m2, agg_v2,
        se_Win, se_g_in, se_b_in, se_m_in, se_v_in, s_ws, psum);
    se_out_kernel<<<dim3(98, 4), 256, 0, stream>>>(s_ws, psum, se_fc1, se_fc2,
        se_Wout, se_g_out, se_b_out, se_m_out, se_v_out, (float*)d_out);
}